// Round 2
// baseline (267.215 us; speedup 1.0000x reference)
//
#include <hip/hip_runtime.h>

// im2col 3x3 SAME, fp32: x (16,64,128,128) -> out (16,128,128,64,3,3)
// out[b,h,w,c,i,j] = x[b,c,h+i-1,w+j-1] (0 if OOB).
//
// Round-2 structure: lane = el = c*9+i*3+j (576 els = 9 waves), LDS layout
// s[el][pw] with odd pixel-stride P=17:
//   - staging writes: lanes walk pw (stride 1)          -> conflict-free
//   - gather reads:   lanes walk el (stride 17, odd)    -> conflict-free
//   - stores: lane=el consecutive -> 256B contiguous dword stores per wave
// (Round-1 had an 8-way LDS read conflict: gather banks were all == 0 mod 4.)

#define WT 16   // pixels per block
#define P  17   // padded pixel stride (odd => stride-P reads conflict-free)

__global__ __launch_bounds__(576)
void im2col_kernel(const float* __restrict__ x, float* __restrict__ out) {
    __shared__ float s[576 * P];  // 39168 B -> 3 blocks/CU, 27 waves/CU

    const int tid = threadIdx.x;
    const int bid = blockIdx.x;
    const int wt = bid & 7;            // W/WT = 8
    const int h  = (bid >> 3) & 127;   // H = 128
    const int b  = bid >> 10;          // 8*128 = 1024 blocks per batch
    const int w0 = wt * WT;

    const float* xb = x + (size_t)b * (64 * 128 * 128);

    // ---- stage + transpose-write: 64c x 3rr x 18cl = 3456 = 576*6 ----
    // value x[c][h-1+rr][w0-1+cl] feeds el = c*9+rr*3+j at pixel pw = cl-j.
#pragma unroll
    for (int k = 0; k < 6; ++k) {
        int si  = tid + k * 576;
        int c   = si / 54;
        int rem = si - c * 54;
        int rr  = rem / 18;
        int cl  = rem - rr * 18;
        int row = h - 1 + rr;
        int col = w0 - 1 + cl;
        float v = 0.0f;
        if ((unsigned)row < 128u && (unsigned)col < 128u)
            v = xb[(c * 128 + row) * 128 + col];
        int elbase = c * 9 + rr * 3;
#pragma unroll
        for (int j = 0; j < 3; ++j) {
            int pw = cl - j;
            if ((unsigned)pw < (unsigned)WT)
                s[(elbase + j) * P + pw] = v;
        }
    }
    __syncthreads();

    // ---- gather (stride-17 reads) + contiguous dword stores ----
    const int el = tid;
    float* ob = out + ((size_t)(b * 128 + h) * 128 + w0) * 576 + el;
    const float* srow = s + el * P;
#pragma unroll
    for (int pw = 0; pw < WT; ++pw) {
        ob[(size_t)pw * 576] = srow[pw];
    }
}

extern "C" void kernel_launch(void* const* d_in, const int* in_sizes, int n_in,
                              void* d_out, int out_size, void* d_ws, size_t ws_size,
                              hipStream_t stream) {
    const float* x = (const float*)d_in[0];
    float* out = (float*)d_out;
    // blocks = 16 b * 128 h * 8 wtiles = 16384
    im2col_kernel<<<16384, 576, 0, stream>>>(x, out);
}

// Round 3
// 209.012 us; speedup vs baseline: 1.2785x; 1.2785x over previous
//
#include <hip/hip_runtime.h>

// im2col 3x3 SAME, fp32: x (16,64,128,128) -> out (16,128,128,64,3,3)
// out[b,h,w,c,i,j] = x[b,c,h+i-1,w+j-1] (0 if OOB).
//
// Round-3 structure: NO LDS, NO barrier. Round 1/2 post-mortem: the
// barrier-phase-locked staging capped store duty cycle (~2.5 TB/s eff.
// write BW vs 6.8 for the barrier-free fill kernel). Here lane = el =
// c*9+i*3+j (576 threads = 9 waves), thread sweeps w:
//   - input addr x[b][c][h+i-1][w+j-1] increments by 4 B per iteration;
//     block's input working set = 64c*3rows = 192 lines = 24 KB -> L1-hot
//     (each line serves 32 sweep iterations).
//   - stores: lane-consecutive el -> 256 B contiguous per wave, same as r2.
//   - no __syncthreads anywhere -> every wave streams stores continuously.
// w=0 / w=127 peeled so the inner loop has no column-bounds check; row
// validity is loop-invariant (cndmask only).

__global__ __launch_bounds__(576)
void im2col_kernel(const float* __restrict__ x, float* __restrict__ out) {
    const int el = threadIdx.x;          // 0..575
    const int bid = blockIdx.x;
    const int h = bid & 127;             // H = 128
    const int b = bid >> 7;

    // decompose el -> (c, i, j), once
    const int c  = el / 9;
    const int ij = el - c * 9;
    const int i  = ij / 3;
    const int j  = ij - i * 3;

    const int row = h + i - 1;
    const bool rv = (unsigned)row < 128u;
    const float* rp = x + ((size_t)b * 64 + c) * 16384 + (rv ? row : 0) * 128;
    const int j1 = j - 1;

    float* ob = out + ((size_t)(b * 128 + h) * 128) * 576 + el;

    // w = 0 (col = j1 may be -1)
    {
        int col = 0 + j1;
        float v = (rv && (unsigned)col < 128u) ? rp[(unsigned)col < 128u ? col : 0] : 0.0f;
        ob[0] = v;
    }
    // w = 1..126: col = w + j1 in [0,127] always
#pragma unroll 4
    for (int w = 1; w < 127; ++w) {
        float v = rp[w + j1];
        v = rv ? v : 0.0f;
        ob[(size_t)w * 576] = v;
    }
    // w = 127 (col may be 128)
    {
        int col = 127 + j1;
        float v = (rv && (unsigned)col < 128u) ? rp[(unsigned)col < 128u ? col : 127] : 0.0f;
        ob[(size_t)127 * 576] = v;
    }
}

extern "C" void kernel_launch(void* const* d_in, const int* in_sizes, int n_in,
                              void* d_out, int out_size, void* d_ws, size_t ws_size,
                              hipStream_t stream) {
    const float* x = (const float*)d_in[0];
    float* out = (float*)d_out;
    // blocks = 16 b * 128 h = 2048; each block does one full (b,h) out-row
    im2col_kernel<<<2048, 576, 0, stream>>>(x, out);
}

// Round 4
// 194.827 us; speedup vs baseline: 1.3715x; 1.0728x over previous
//
#include <hip/hip_runtime.h>

// im2col 3x3 SAME, fp32: x (16,64,128,128) -> out (16,128,128,64,3,3)
// out[b,h,w,c,i,j] = x[b,c,h+i-1,w+j-1] (0 if OOB).
//
// Round-4: round-3 structure (no LDS, no barrier, lane = el = c*9+i*3+j,
// thread sweeps w; stores 256 B contiguous per wave) + float4 input loads.
// Round-3 limiter model: 2.36M gather wave-loads x ~22 L1-line transactions
// ~= 84 us of TA pipe time. One dwordx4 per 4 w-iterations cuts load
// instructions 4x (transactions ~3x) -> TA ~27 us << HBM ~100 us floor.
// w=0 and w=125..127 peeled: vector body has no column clamp and never
// dereferences rp[-1].

typedef float f4 __attribute__((ext_vector_type(4), aligned(4)));

__global__ __launch_bounds__(576)
void im2col_kernel(const float* __restrict__ x, float* __restrict__ out) {
    const int el = threadIdx.x;          // 0..575
    const int bid = blockIdx.x;
    const int h = bid & 127;             // H = 128
    const int b = bid >> 7;

    // el -> (c, i, j), once
    const int c  = el / 9;
    const int ij = el - c * 9;
    const int i  = ij / 3;
    const int j  = ij - i * 3;

    const int row = h + i - 1;
    const bool rv = (unsigned)row < 128u;
    const float* rp = x + ((size_t)b * 64 + c) * 16384 + (rv ? row : 0) * 128;
    const int j1 = j - 1;

    float* ob = out + (size_t)bid * (128 * 576) + el;

    // ---- w = 0 (col = j1 may be -1) ----
    {
        int col = j1;
        float v = rp[col < 0 ? 0 : col];
        ob[0] = (rv && col >= 0) ? v : 0.0f;
    }

    // ---- w = 1..124: 31 x { one float4 load, four dword stores } ----
    // cols w+j1 .. w+j1+3 are within [0,127] for all j when 1 <= w <= 121+3.
#pragma unroll 4
    for (int it = 0; it < 31; ++it) {
        int w = 1 + (it << 2);
        f4 v = *(const f4*)(rp + w + j1);   // 4B-aligned dwordx4
        if (!rv) { v.x = 0.0f; v.y = 0.0f; v.z = 0.0f; v.w = 0.0f; }
        float* o = ob + (size_t)w * 576;
        o[0]        = v.x;
        o[576]      = v.y;
        o[2 * 576]  = v.z;
        o[3 * 576]  = v.w;
    }

    // ---- w = 125..127 (col may reach 128) ----
#pragma unroll
    for (int w = 125; w < 128; ++w) {
        int col = w + j1;
        float v = rp[col > 127 ? 127 : col];
        ob[(size_t)w * 576] = (rv && col <= 127) ? v : 0.0f;
    }
}

extern "C" void kernel_launch(void* const* d_in, const int* in_sizes, int n_in,
                              void* d_out, int out_size, void* d_ws, size_t ws_size,
                              hipStream_t stream) {
    const float* x = (const float*)d_in[0];
    float* out = (float*)d_out;
    // blocks = 16 b * 128 h = 2048; each block emits one full (b,h) out-row
    im2col_kernel<<<2048, 576, 0, stream>>>(x, out);
}